// Round 4
// baseline (470.811 us; speedup 1.0000x reference)
//
#include <hip/hip_runtime.h>

typedef unsigned short u16;
typedef __bf16 bf16x8 __attribute__((ext_vector_type(8)));
typedef short s16x4 __attribute__((ext_vector_type(4)));
typedef float f32x4 __attribute__((ext_vector_type(4)));

// ---------- helpers ----------
__device__ __forceinline__ u16 f2bf(float f) {
  unsigned u = __float_as_uint(f);
  unsigned r = u + 0x7fffu + ((u >> 16) & 1u);   // RNE
  return (u16)(r >> 16);
}

// pack two positive f32 -> two bf16 (round-half-up) in one dword via v_perm
__device__ __forceinline__ unsigned pack2bf(float a, float b) {
  return __builtin_amdgcn_perm(__float_as_uint(b) + 0x8000u,
                               __float_as_uint(a) + 0x8000u, 0x07060302u);
}

__device__ __forceinline__ void async_cp16(const void* g, void* l) {
  __builtin_amdgcn_global_load_lds((__attribute__((address_space(1))) void*)g,
                                   (__attribute__((address_space(3))) void*)l,
                                   16, 0, 0);
}

#define MFMA32(a, b, c) __builtin_amdgcn_mfma_f32_16x16x32_bf16(a, b, c, 0, 0, 0)

#if __has_builtin(__builtin_amdgcn_mfma_f32_16x16x16bf16_1k)
#define MFMA16(a, b, c) __builtin_amdgcn_mfma_f32_16x16x16bf16_1k(a, b, c, 0, 0, 0)
#else
__device__ __forceinline__ f32x4 mfma16_fb(s16x4 a, s16x4 b, f32x4 c) {
  asm("v_mfma_f32_16x16x16_bf16 %0, %1, %2, %0" : "+v"(c) : "v"(a), "v"(b));
  return c;
}
#define MFMA16(a, b, c) mfma16_fb(a, b, c)
#endif

// ---------- fused LayerNorm + bf16 cast ----------
__global__ __launch_bounds__(256)
void ln_cast(const float* __restrict__ X, const float* __restrict__ W,
             const float* __restrict__ Bv, u16* __restrict__ Y) {
  __shared__ float red[8];
  const int row = blockIdx.x, t = threadIdx.x;
  const int wave = t >> 6, lane = t & 63;
  const float4 v = ((const float4*)(X + (size_t)row * 1024))[t];
  float s  = v.x + v.y + v.z + v.w;
  float ss = v.x*v.x + v.y*v.y + v.z*v.z + v.w*v.w;
#pragma unroll
  for (int m = 32; m; m >>= 1) { s += __shfl_xor(s, m, 64); ss += __shfl_xor(ss, m, 64); }
  if (lane == 0) { red[wave] = s; red[4 + wave] = ss; }
  __syncthreads();
  float S  = red[0] + red[1] + red[2] + red[3];
  float SS = red[4] + red[5] + red[6] + red[7];
  float mu  = S * (1.0f / 1024.0f);
  float var = SS * (1.0f / 1024.0f) - mu * mu;
  float rstd = rsqrtf(var + 1e-5f);
  const float4 wv = ((const float4*)W)[t];
  const float4 bv = ((const float4*)Bv)[t];
  ushort4 o;
  o.x = f2bf((v.x - mu) * rstd * wv.x + bv.x);
  o.y = f2bf((v.y - mu) * rstd * wv.y + bv.y);
  o.z = f2bf((v.z - mu) * rstd * wv.z + bv.z);
  o.w = f2bf((v.w - mu) * rstd * wv.w + bv.w);
  ((ushort4*)(Y + (size_t)row * 1024))[t] = o;
}

// ---------- weight transpose + cast: W[K][N] f32 -> WT[N][K] bf16 ----------
__global__ __launch_bounds__(256)
void wtrans(const float* __restrict__ W, u16* __restrict__ WT) {
  __shared__ float t[64][65];
  const int k0 = blockIdx.y * 64, n0 = blockIdx.x * 64;
  const int lr = threadIdx.x >> 4, lc = threadIdx.x & 15;
#pragma unroll
  for (int r = 0; r < 4; ++r) {
    int row = r * 16 + lr;
    float4 v = *(const float4*)(W + (size_t)(k0 + row) * 1024 + n0 + lc * 4);
    t[row][lc*4+0] = v.x; t[row][lc*4+1] = v.y; t[row][lc*4+2] = v.z; t[row][lc*4+3] = v.w;
  }
  __syncthreads();
#pragma unroll
  for (int r = 0; r < 4; ++r) {
    int n = r * 16 + lr;
    ushort4 o;
    o.x = f2bf(t[lc*4+0][n]); o.y = f2bf(t[lc*4+1][n]);
    o.z = f2bf(t[lc*4+2][n]); o.w = f2bf(t[lc*4+3][n]);
    *(ushort4*)(WT + (size_t)(n0 + n) * 1024 + k0 + lc * 4) = o;
  }
}

// ---------- V transpose: V[b][kk][h][d] f32 -> VT[b][h][d][kk] bf16 ----------
__global__ __launch_bounds__(256)
void vtrans(const float* __restrict__ V, u16* __restrict__ VT) {
  __shared__ float t[64][65];
  const int b = blockIdx.z, h = blockIdx.y, kk0 = blockIdx.x * 64;
  const int lr = threadIdx.x >> 4, lc = threadIdx.x & 15;
#pragma unroll
  for (int r = 0; r < 4; ++r) {
    int row = r * 16 + lr;
    float4 v = *(const float4*)(V + (size_t)(b * 2048 + kk0 + row) * 1024 + h * 64 + lc * 4);
    t[row][lc*4+0] = v.x; t[row][lc*4+1] = v.y; t[row][lc*4+2] = v.z; t[row][lc*4+3] = v.w;
  }
  __syncthreads();
#pragma unroll
  for (int r = 0; r < 4; ++r) {
    int d = r * 16 + lr;
    ushort4 o;
    o.x = f2bf(t[lc*4+0][d]); o.y = f2bf(t[lc*4+1][d]);
    o.z = f2bf(t[lc*4+2][d]); o.w = f2bf(t[lc*4+3][d]);
    *(ushort4*)(VT + ((size_t)(b * 16 + h) * 64 + d) * 2048 + kk0 + lc * 4) = o;
  }
}

// ---------- GEMM: C[M][N] f32 = A[M][K] bf16 x BT[N][K] bf16 (m97 structure) ----------
__global__ __launch_bounds__(256, 2)
void gemm_bt(const u16* __restrict__ A, const u16* __restrict__ Bt,
             float* __restrict__ C, int M, int N, int K) {
  __shared__ __align__(16) u16 As[128 * 64];
  __shared__ __align__(16) u16 Bs[128 * 64];
  const int tid = threadIdx.x;
  const int wave = tid >> 6, lane = tid & 63;
  const int quad = lane >> 4, l15 = lane & 15;
  const int m0 = blockIdx.y * 128, n0 = blockIdx.x * 128;
  const int wm = (wave >> 1) * 64, wn = (wave & 1) * 64;
  const int srow = lane >> 3, scol = (lane & 7) * 8;

  const f32x4 fz = {0.f, 0.f, 0.f, 0.f};
  f32x4 acc[4][4];
#pragma unroll
  for (int i = 0; i < 4; ++i)
#pragma unroll
    for (int j = 0; j < 4; ++j) acc[i][j] = fz;

  for (int kt = 0; kt < K; kt += 64) {
    __syncthreads();
#pragma unroll
    for (int r = 0; r < 4; ++r) {
      const int c = r * 4 + wave;
      const int row = c * 8 + srow;
      async_cp16(A  + (size_t)(m0 + row) * K + kt + scol, (char*)As + c * 1024);
      async_cp16(Bt + (size_t)(n0 + row) * K + kt + scol, (char*)Bs + c * 1024);
    }
    __syncthreads();
#pragma unroll
    for (int ks = 0; ks < 2; ++ks) {
      bf16x8 af[4], bfr[4];
#pragma unroll
      for (int i = 0; i < 4; ++i)
        af[i] = *(const bf16x8*)(const void*)(As + (wm + i * 16 + l15) * 64 + ks * 32 + quad * 8);
#pragma unroll
      for (int j = 0; j < 4; ++j)
        bfr[j] = *(const bf16x8*)(const void*)(Bs + (wn + j * 16 + l15) * 64 + ks * 32 + quad * 8);
#pragma unroll
      for (int i = 0; i < 4; ++i)
#pragma unroll
        for (int j = 0; j < 4; ++j)
          acc[i][j] = MFMA32(af[i], bfr[j], acc[i][j]);
    }
  }
#pragma unroll
  for (int i = 0; i < 4; ++i)
#pragma unroll
    for (int j = 0; j < 4; ++j)
#pragma unroll
      for (int e = 0; e < 4; ++e) {
        int row = m0 + wm + i * 16 + quad * 4 + e;
        int col = n0 + wn + j * 16 + l15;
        C[(size_t)row * N + col] = acc[i][j][e];
      }
}

// ---------- GEMM + fused per-head l2norm epilogue -> bf16 ----------
// Each wave's 64-col strip is exactly one head (N=1024, 16 heads x 64).
// scaled=1 additionally folds log2e/(tau+eps) into the row scale (for Q).
__global__ __launch_bounds__(256, 2)
void gemm_l2n(const u16* __restrict__ A, const u16* __restrict__ Bt,
              u16* __restrict__ Y, const float* __restrict__ taup, int scaled) {
  __shared__ __align__(16) u16 As[128 * 64];
  __shared__ __align__(16) u16 Bs[128 * 64];
  const int tid = threadIdx.x;
  const int wave = tid >> 6, lane = tid & 63;
  const int quad = lane >> 4, l15 = lane & 15;
  const int m0 = blockIdx.y * 128, n0 = blockIdx.x * 128;
  const int wm = (wave >> 1) * 64, wn = (wave & 1) * 64;
  const int srow = lane >> 3, scol = (lane & 7) * 8;
  const int K = 1024, N = 1024;

  const f32x4 fz = {0.f, 0.f, 0.f, 0.f};
  f32x4 acc[4][4];
#pragma unroll
  for (int i = 0; i < 4; ++i)
#pragma unroll
    for (int j = 0; j < 4; ++j) acc[i][j] = fz;

  for (int kt = 0; kt < K; kt += 64) {
    __syncthreads();
#pragma unroll
    for (int r = 0; r < 4; ++r) {
      const int c = r * 4 + wave;
      const int row = c * 8 + srow;
      async_cp16(A  + (size_t)(m0 + row) * K + kt + scol, (char*)As + c * 1024);
      async_cp16(Bt + (size_t)(n0 + row) * K + kt + scol, (char*)Bs + c * 1024);
    }
    __syncthreads();
#pragma unroll
    for (int ks = 0; ks < 2; ++ks) {
      bf16x8 af[4], bfr[4];
#pragma unroll
      for (int i = 0; i < 4; ++i)
        af[i] = *(const bf16x8*)(const void*)(As + (wm + i * 16 + l15) * 64 + ks * 32 + quad * 8);
#pragma unroll
      for (int j = 0; j < 4; ++j)
        bfr[j] = *(const bf16x8*)(const void*)(Bs + (wn + j * 16 + l15) * 64 + ks * 32 + quad * 8);
#pragma unroll
      for (int i = 0; i < 4; ++i)
#pragma unroll
        for (int j = 0; j < 4; ++j)
          acc[i][j] = MFMA32(af[i], bfr[j], acc[i][j]);
    }
  }
  const float tsc = scaled ? 1.44269504f / (taup[0] + 1e-6f) : 1.0f;
#pragma unroll
  for (int i = 0; i < 4; ++i)
#pragma unroll
    for (int e = 0; e < 4; ++e) {
      float ss = 0.f;
#pragma unroll
      for (int j = 0; j < 4; ++j) ss = fmaf(acc[i][j][e], acc[i][j][e], ss);
      ss += __shfl_xor(ss, 1, 64); ss += __shfl_xor(ss, 2, 64);
      ss += __shfl_xor(ss, 4, 64); ss += __shfl_xor(ss, 8, 64);
      float sc = tsc / fmaxf(sqrtf(ss), 1e-12f);
      int row = m0 + wm + i * 16 + quad * 4 + e;
#pragma unroll
      for (int j = 0; j < 4; ++j)
        Y[(size_t)row * N + n0 + wn + j * 16 + l15] = f2bf(acc[i][j][e] * sc);
    }
}

// ---------- flash attention v3: S^T trick, P stays in registers ----------
// S^T = K.Q^T via mfma(kb, aq): C/D layout (kk=quad*4+e, q=l15) == B-operand
// layout of 16x16x16 MFMA -> PV (O^T = V^T.P^T) runs with zero LDS for P.
__global__ __launch_bounds__(256, 2)
void flash_attn3(const u16* __restrict__ Qb, const u16* __restrict__ Kb,
                 const u16* __restrict__ Vt, const int* __restrict__ mask,
                 u16* __restrict__ Ob) {
  __shared__ __align__(16) u16 QPs[256 * 72];   // Q staging (stride 64), epilogue scratch (stride 72)
  __shared__ __align__(16) u16 Ks[64 * 64];     // K tile [kk][d]
  __shared__ __align__(16) u16 Vs[64 * 64];     // V^T tile [d][kk]
  __shared__ __align__(16) int Mshi[2048];
  const int tid = threadIdx.x, w = tid >> 6, lane = tid & 63;
  const int quad = lane >> 4, l15 = lane & 15;
  const int b = blockIdx.z, h = blockIdx.y, q0 = blockIdx.x * 256;
  const int srow = lane >> 3, scol = (lane & 7) * 8;

  // stage Q tile (256x64, stride 64) + mask ints
#pragma unroll
  for (int r = 0; r < 8; ++r) {
    int c = w * 8 + r;
    async_cp16(Qb + (size_t)(b * 2048 + q0 + c * 8 + srow) * 1024 + h * 64 + scol,
               (char*)QPs + c * 1024);
  }
#pragma unroll
  for (int r = 0; r < 2; ++r) {
    int c = w * 2 + r;
    async_cp16(mask + b * 2048 + c * 256 + lane * 4, (char*)Mshi + c * 1024);
  }
  __syncthreads();

  // Q fragments in registers (wave's own 64 rows); also valid as B-operand of S^T
  bf16x8 aq[4][2];
#pragma unroll
  for (int i = 0; i < 4; ++i)
#pragma unroll
    for (int ks = 0; ks < 2; ++ks)
      aq[i][ks] = *(const bf16x8*)(const void*)(QPs + (w * 64 + i * 16 + l15) * 64 + ks * 32 + quad * 8);

  const f32x4 fz = {0.f, 0.f, 0.f, 0.f};
  f32x4 o[4][4];                 // O^T accum: [d-tile][q-tile], row d=quad*4+e, col q=l15
  float rs[4] = {0.f, 0.f, 0.f, 0.f};   // per-lane partial row sums, q=l15 (+16i), kk-share by quad
#pragma unroll
  for (int dt = 0; dt < 4; ++dt)
#pragma unroll
    for (int i = 0; i < 4; ++i) o[dt][i] = fz;

  for (int kt = 0; kt < 2048; kt += 64) {
    __syncthreads();
#pragma unroll
    for (int r = 0; r < 2; ++r) {
      int c = w * 2 + r;
      async_cp16(Kb + (size_t)(b * 2048 + kt + c * 8 + srow) * 1024 + h * 64 + scol,
                 (char*)Ks + c * 1024);
      async_cp16(Vt + ((size_t)(b * 16 + h) * 64 + c * 8 + srow) * 2048 + kt + scol,
                 (char*)Vs + c * 1024);
    }
    __syncthreads();

    bf16x8 kb[4][2];             // K A-frags: m=kk=l15, k=d
#pragma unroll
    for (int kkt = 0; kkt < 4; ++kkt)
#pragma unroll
      for (int ks = 0; ks < 2; ++ks)
        kb[kkt][ks] = *(const bf16x8*)(const void*)(Ks + (kkt * 16 + l15) * 64 + ks * 32 + quad * 8);

#pragma unroll
    for (int kkt = 0; kkt < 4; ++kkt) {
      // mask multipliers for this lane's 4 kk rows (broadcast read)
      int4 mi = *(const int4*)(Mshi + kt + kkt * 16 + quad * 4);
      float m0 = (float)(mi.x ^ 1), m1 = (float)(mi.y ^ 1);
      float m2 = (float)(mi.z ^ 1), m3 = (float)(mi.w ^ 1);

      s16x4 pf[4];
#pragma unroll
      for (int i = 0; i < 4; ++i) {
        f32x4 st = MFMA32(kb[kkt][0], aq[i][0], fz);
        st = MFMA32(kb[kkt][1], aq[i][1], st);
        float p0 = exp2f(st[0]) * m0, p1 = exp2f(st[1]) * m1;
        float p2 = exp2f(st[2]) * m2, p3 = exp2f(st[3]) * m3;
        rs[i] += (p0 + p1) + (p2 + p3);
        union { unsigned u[2]; s16x4 s; } pk;
        pk.u[0] = pack2bf(p0, p1);
        pk.u[1] = pack2bf(p2, p3);
        pf[i] = pk.s;
      }
#pragma unroll
      for (int dt = 0; dt < 4; ++dt) {
        s16x4 va = *(const s16x4*)(const void*)(Vs + (dt * 16 + l15) * 64 + kkt * 16 + quad * 4);
#pragma unroll
        for (int i = 0; i < 4; ++i)
          o[dt][i] = MFMA16(va, pf[i], o[dt][i]);
      }
    }
  }

  // row sums: reduce the 4 quad-partitions
  float inv[4];
#pragma unroll
  for (int i = 0; i < 4; ++i) {
    float v = rs[i];
    v += __shfl_xor(v, 16, 64);
    v += __shfl_xor(v, 32, 64);
    inv[i] = 1.0f / v;
  }

  // epilogue: un-transpose O^T via wave-private LDS strip (stride 72 u16 = 144B, 16B-aligned)
  u16* strip = QPs + w * 64 * 72;
#pragma unroll
  for (int dt = 0; dt < 4; ++dt)
#pragma unroll
    for (int i = 0; i < 4; ++i) {
      union { unsigned u[2]; s16x4 s; } pk;
      pk.u[0] = pack2bf(o[dt][i][0] * inv[i], o[dt][i][1] * inv[i]);
      pk.u[1] = pack2bf(o[dt][i][2] * inv[i], o[dt][i][3] * inv[i]);
      *(s16x4*)(void*)(strip + (i * 16 + l15) * 72 + dt * 16 + quad * 4) = pk.s;
    }
  // coalesced store: 8 lanes x 16B per q-row
#pragma unroll
  for (int pass = 0; pass < 8; ++pass) {
    int row = pass * 8 + (lane >> 3), oct = lane & 7;
    int4 v = *(const int4*)(const void*)(strip + row * 72 + oct * 8);
    *(int4*)(Ob + (size_t)(b * 2048 + q0 + w * 64 + row) * 1024 + h * 64 + oct * 8) = v;
  }
}

// ---------- launch ----------
extern "C" void kernel_launch(void* const* d_in, const int* in_sizes, int n_in,
                              void* d_out, int out_size, void* d_ws, size_t ws_size,
                              hipStream_t stream) {
  const float* x    = (const float*)d_in[0];
  const float* ctx  = (const float*)d_in[1];
  const int*   mask = (const int*)d_in[2];
  const float* lnqw = (const float*)d_in[3];
  const float* lnqb = (const float*)d_in[4];
  const float* lncw = (const float*)d_in[5];
  const float* lncb = (const float*)d_in[6];
  const float* Wq   = (const float*)d_in[7];
  const float* Wk   = (const float*)d_in[8];
  const float* Wv   = (const float*)d_in[9];
  const float* Wo   = (const float*)d_in[10];
  const float* tau  = (const float*)d_in[11];
  float* out = (float*)d_out;
  char* ws = (char*)d_ws;
  const size_t MB = 1024 * 1024;

  u16* qin  = (u16*)(ws + 0 * MB);    // 16 MB; reused as attn-out later
  u16* kvin = (u16*)(ws + 16 * MB);   // 16 MB
  u16* WqT  = (u16*)(ws + 32 * MB);   // 2 MB each
  u16* WkT  = (u16*)(ws + 34 * MB);
  u16* WvT  = (u16*)(ws + 36 * MB);
  u16* WoT  = (u16*)(ws + 38 * MB);
  u16* qbf  = (u16*)(ws + 40 * MB);   // 16 MB
  u16* kbf  = (u16*)(ws + 56 * MB);   // 16 MB
  u16* vT   = (u16*)(ws + 72 * MB);   // 16 MB  (total 88 MB — proven footprint)
  float* scr = out;                   // d_out (32 MB f32) as V-projection scratch
  u16* attn = qin;                    // qin dead after first GEMM

  ln_cast<<<8192, 256, 0, stream>>>(x,   lnqw, lnqb, qin);
  ln_cast<<<8192, 256, 0, stream>>>(ctx, lncw, lncb, kvin);
  wtrans<<<dim3(16, 16), 256, 0, stream>>>(Wq, WqT);
  wtrans<<<dim3(16, 16), 256, 0, stream>>>(Wk, WkT);
  wtrans<<<dim3(16, 16), 256, 0, stream>>>(Wv, WvT);
  wtrans<<<dim3(16, 16), 256, 0, stream>>>(Wo, WoT);

  gemm_l2n<<<dim3(8, 64), 256, 0, stream>>>(qin,  WqT, qbf, tau, 1);
  gemm_l2n<<<dim3(8, 64), 256, 0, stream>>>(kvin, WkT, kbf, tau, 0);

  gemm_bt<<<dim3(8, 64), 256, 0, stream>>>(kvin, WvT, scr, 8192, 1024, 1024);
  vtrans<<<dim3(32, 16, 4), 256, 0, stream>>>(scr, vT);

  flash_attn3<<<dim3(8, 16, 4), 256, 0, stream>>>(qbf, kbf, vT, mask, attn);

  gemm_bt<<<dim3(8, 64), 256, 0, stream>>>(attn, WoT, out, 8192, 1024, 1024);
}

// Round 5
// 415.555 us; speedup vs baseline: 1.1330x; 1.1330x over previous
//
#include <hip/hip_runtime.h>

typedef unsigned short u16;
typedef __bf16 bf16x8 __attribute__((ext_vector_type(8)));
typedef short s16x4 __attribute__((ext_vector_type(4)));
typedef float f32x4 __attribute__((ext_vector_type(4)));

// ---------- helpers ----------
__device__ __forceinline__ u16 f2bf(float f) {
  unsigned u = __float_as_uint(f);
  unsigned r = u + 0x7fffu + ((u >> 16) & 1u);   // RNE
  return (u16)(r >> 16);
}

// pack two positive f32 -> two bf16 (round-half-up) in one dword via v_perm
__device__ __forceinline__ unsigned pack2bf(float a, float b) {
  return __builtin_amdgcn_perm(__float_as_uint(b) + 0x8000u,
                               __float_as_uint(a) + 0x8000u, 0x07060302u);
}

__device__ __forceinline__ void async_cp16(const void* g, void* l) {
  __builtin_amdgcn_global_load_lds((__attribute__((address_space(1))) void*)g,
                                   (__attribute__((address_space(3))) void*)l,
                                   16, 0, 0);
}

#define MFMA32(a, b, c) __builtin_amdgcn_mfma_f32_16x16x32_bf16(a, b, c, 0, 0, 0)

#if __has_builtin(__builtin_amdgcn_mfma_f32_16x16x16bf16_1k)
#define MFMA16(a, b, c) __builtin_amdgcn_mfma_f32_16x16x16bf16_1k(a, b, c, 0, 0, 0)
#else
__device__ __forceinline__ f32x4 mfma16_fb(s16x4 a, s16x4 b, f32x4 c) {
  asm("v_mfma_f32_16x16x16_bf16 %0, %1, %2, %0" : "+v"(c) : "v"(a), "v"(b));
  return c;
}
#define MFMA16(a, b, c) mfma16_fb(a, b, c)
#endif

// ---------- fused LayerNorm + bf16 cast ----------
__global__ __launch_bounds__(256)
void ln_cast(const float* __restrict__ X, const float* __restrict__ W,
             const float* __restrict__ Bv, u16* __restrict__ Y) {
  __shared__ float red[8];
  const int row = blockIdx.x, t = threadIdx.x;
  const int wave = t >> 6, lane = t & 63;
  const float4 v = ((const float4*)(X + (size_t)row * 1024))[t];
  float s  = v.x + v.y + v.z + v.w;
  float ss = v.x*v.x + v.y*v.y + v.z*v.z + v.w*v.w;
#pragma unroll
  for (int m = 32; m; m >>= 1) { s += __shfl_xor(s, m, 64); ss += __shfl_xor(ss, m, 64); }
  if (lane == 0) { red[wave] = s; red[4 + wave] = ss; }
  __syncthreads();
  float S  = red[0] + red[1] + red[2] + red[3];
  float SS = red[4] + red[5] + red[6] + red[7];
  float mu  = S * (1.0f / 1024.0f);
  float var = SS * (1.0f / 1024.0f) - mu * mu;
  float rstd = rsqrtf(var + 1e-5f);
  const float4 wv = ((const float4*)W)[t];
  const float4 bv = ((const float4*)Bv)[t];
  ushort4 o;
  o.x = f2bf((v.x - mu) * rstd * wv.x + bv.x);
  o.y = f2bf((v.y - mu) * rstd * wv.y + bv.y);
  o.z = f2bf((v.z - mu) * rstd * wv.z + bv.z);
  o.w = f2bf((v.w - mu) * rstd * wv.w + bv.w);
  ((ushort4*)(Y + (size_t)row * 1024))[t] = o;
}

// ---------- weight transpose + cast: W[K][N] f32 -> WT[N][K] bf16 ----------
__global__ __launch_bounds__(256)
void wtrans(const float* __restrict__ W, u16* __restrict__ WT) {
  __shared__ float t[64][65];
  const int k0 = blockIdx.y * 64, n0 = blockIdx.x * 64;
  const int lr = threadIdx.x >> 4, lc = threadIdx.x & 15;
#pragma unroll
  for (int r = 0; r < 4; ++r) {
    int row = r * 16 + lr;
    float4 v = *(const float4*)(W + (size_t)(k0 + row) * 1024 + n0 + lc * 4);
    t[row][lc*4+0] = v.x; t[row][lc*4+1] = v.y; t[row][lc*4+2] = v.z; t[row][lc*4+3] = v.w;
  }
  __syncthreads();
#pragma unroll
  for (int r = 0; r < 4; ++r) {
    int n = r * 16 + lr;
    ushort4 o;
    o.x = f2bf(t[lc*4+0][n]); o.y = f2bf(t[lc*4+1][n]);
    o.z = f2bf(t[lc*4+2][n]); o.w = f2bf(t[lc*4+3][n]);
    *(ushort4*)(WT + (size_t)(n0 + n) * 1024 + k0 + lc * 4) = o;
  }
}

// ---------- V transpose: V[b][kk][h][d] f32 -> VT[b][h][d][kk] bf16 ----------
__global__ __launch_bounds__(256)
void vtrans(const float* __restrict__ V, u16* __restrict__ VT) {
  __shared__ float t[64][65];
  const int b = blockIdx.z, h = blockIdx.y, kk0 = blockIdx.x * 64;
  const int lr = threadIdx.x >> 4, lc = threadIdx.x & 15;
#pragma unroll
  for (int r = 0; r < 4; ++r) {
    int row = r * 16 + lr;
    float4 v = *(const float4*)(V + (size_t)(b * 2048 + kk0 + row) * 1024 + h * 64 + lc * 4);
    t[row][lc*4+0] = v.x; t[row][lc*4+1] = v.y; t[row][lc*4+2] = v.z; t[row][lc*4+3] = v.w;
  }
  __syncthreads();
#pragma unroll
  for (int r = 0; r < 4; ++r) {
    int d = r * 16 + lr;
    ushort4 o;
    o.x = f2bf(t[lc*4+0][d]); o.y = f2bf(t[lc*4+1][d]);
    o.z = f2bf(t[lc*4+2][d]); o.w = f2bf(t[lc*4+3][d]);
    *(ushort4*)(VT + ((size_t)(b * 16 + h) * 64 + d) * 2048 + kk0 + lc * 4) = o;
  }
}

// ---------- GEMM: C[M][N] f32 = A[M][K] bf16 x BT[N][K] bf16 (m97 structure) ----------
__global__ __launch_bounds__(256, 2)
void gemm_bt(const u16* __restrict__ A, const u16* __restrict__ Bt,
             float* __restrict__ C, int M, int N, int K) {
  __shared__ __align__(16) u16 As[128 * 64];
  __shared__ __align__(16) u16 Bs[128 * 64];
  const int tid = threadIdx.x;
  const int wave = tid >> 6, lane = tid & 63;
  const int quad = lane >> 4, l15 = lane & 15;
  const int m0 = blockIdx.y * 128, n0 = blockIdx.x * 128;
  const int wm = (wave >> 1) * 64, wn = (wave & 1) * 64;
  const int srow = lane >> 3, scol = (lane & 7) * 8;

  const f32x4 fz = {0.f, 0.f, 0.f, 0.f};
  f32x4 acc[4][4];
#pragma unroll
  for (int i = 0; i < 4; ++i)
#pragma unroll
    for (int j = 0; j < 4; ++j) acc[i][j] = fz;

  for (int kt = 0; kt < K; kt += 64) {
    __syncthreads();
#pragma unroll
    for (int r = 0; r < 4; ++r) {
      const int c = r * 4 + wave;
      const int row = c * 8 + srow;
      async_cp16(A  + (size_t)(m0 + row) * K + kt + scol, (char*)As + c * 1024);
      async_cp16(Bt + (size_t)(n0 + row) * K + kt + scol, (char*)Bs + c * 1024);
    }
    __syncthreads();
#pragma unroll
    for (int ks = 0; ks < 2; ++ks) {
      bf16x8 af[4], bfr[4];
#pragma unroll
      for (int i = 0; i < 4; ++i)
        af[i] = *(const bf16x8*)(const void*)(As + (wm + i * 16 + l15) * 64 + ks * 32 + quad * 8);
#pragma unroll
      for (int j = 0; j < 4; ++j)
        bfr[j] = *(const bf16x8*)(const void*)(Bs + (wn + j * 16 + l15) * 64 + ks * 32 + quad * 8);
#pragma unroll
      for (int i = 0; i < 4; ++i)
#pragma unroll
        for (int j = 0; j < 4; ++j)
          acc[i][j] = MFMA32(af[i], bfr[j], acc[i][j]);
    }
  }
#pragma unroll
  for (int i = 0; i < 4; ++i)
#pragma unroll
    for (int j = 0; j < 4; ++j)
#pragma unroll
      for (int e = 0; e < 4; ++e) {
        int row = m0 + wm + i * 16 + quad * 4 + e;
        int col = n0 + wn + j * 16 + l15;
        C[(size_t)row * N + col] = acc[i][j][e];
      }
}

// ---------- GEMM + fused per-head l2norm epilogue -> bf16 ----------
// Each wave's 64-col strip is exactly one head (N=1024, 16 heads x 64).
// scaled=1 additionally folds log2e/(tau+eps) into the row scale (for Q).
__global__ __launch_bounds__(256, 2)
void gemm_l2n(const u16* __restrict__ A, const u16* __restrict__ Bt,
              u16* __restrict__ Y, const float* __restrict__ taup, int scaled) {
  __shared__ __align__(16) u16 As[128 * 64];
  __shared__ __align__(16) u16 Bs[128 * 64];
  const int tid = threadIdx.x;
  const int wave = tid >> 6, lane = tid & 63;
  const int quad = lane >> 4, l15 = lane & 15;
  const int m0 = blockIdx.y * 128, n0 = blockIdx.x * 128;
  const int wm = (wave >> 1) * 64, wn = (wave & 1) * 64;
  const int srow = lane >> 3, scol = (lane & 7) * 8;
  const int K = 1024, N = 1024;

  const f32x4 fz = {0.f, 0.f, 0.f, 0.f};
  f32x4 acc[4][4];
#pragma unroll
  for (int i = 0; i < 4; ++i)
#pragma unroll
    for (int j = 0; j < 4; ++j) acc[i][j] = fz;

  for (int kt = 0; kt < K; kt += 64) {
    __syncthreads();
#pragma unroll
    for (int r = 0; r < 4; ++r) {
      const int c = r * 4 + wave;
      const int row = c * 8 + srow;
      async_cp16(A  + (size_t)(m0 + row) * K + kt + scol, (char*)As + c * 1024);
      async_cp16(Bt + (size_t)(n0 + row) * K + kt + scol, (char*)Bs + c * 1024);
    }
    __syncthreads();
#pragma unroll
    for (int ks = 0; ks < 2; ++ks) {
      bf16x8 af[4], bfr[4];
#pragma unroll
      for (int i = 0; i < 4; ++i)
        af[i] = *(const bf16x8*)(const void*)(As + (wm + i * 16 + l15) * 64 + ks * 32 + quad * 8);
#pragma unroll
      for (int j = 0; j < 4; ++j)
        bfr[j] = *(const bf16x8*)(const void*)(Bs + (wn + j * 16 + l15) * 64 + ks * 32 + quad * 8);
#pragma unroll
      for (int i = 0; i < 4; ++i)
#pragma unroll
        for (int j = 0; j < 4; ++j)
          acc[i][j] = MFMA32(af[i], bfr[j], acc[i][j]);
    }
  }
  const float tsc = scaled ? 1.44269504f / (taup[0] + 1e-6f) : 1.0f;
#pragma unroll
  for (int i = 0; i < 4; ++i)
#pragma unroll
    for (int e = 0; e < 4; ++e) {
      float ss = 0.f;
#pragma unroll
      for (int j = 0; j < 4; ++j) ss = fmaf(acc[i][j][e], acc[i][j][e], ss);
      ss += __shfl_xor(ss, 1, 64); ss += __shfl_xor(ss, 2, 64);
      ss += __shfl_xor(ss, 4, 64); ss += __shfl_xor(ss, 8, 64);
      float sc = tsc / fmaxf(sqrtf(ss), 1e-12f);
      int row = m0 + wm + i * 16 + quad * 4 + e;
#pragma unroll
      for (int j = 0; j < 4; ++j)
        Y[(size_t)row * N + n0 + wn + j * 16 + l15] = f2bf(acc[i][j][e] * sc);
    }
}

// ---------- flash attention v4: S^T trick, register P, padded V tile ----------
// S^T = K.Q^T: C/D layout (kk=quad*4+e, q=l15) == B-operand of 16x16x16 MFMA
// -> PV (O^T = V^T.P^T) with P never touching LDS.
// V tile staged via VGPR round-trip into stride-72 rows: bank = (l15*4+kkt*8+quad*2)%32
// -> only 2-way aliasing (free, m136) on the b64 A-frag reads, vs 16-way at stride 64.
__global__ __launch_bounds__(256, 2)
void flash_attn4(const u16* __restrict__ Qb, const u16* __restrict__ Kb,
                 const u16* __restrict__ Vt, const int* __restrict__ mask,
                 u16* __restrict__ Ob) {
  __shared__ __align__(16) u16 QPs[256 * 72];   // Q staging (stride 64), epilogue scratch (stride 72)
  __shared__ __align__(16) u16 Ks[64 * 64];     // K tile [kk][d], stride 64 (async-staged)
  __shared__ __align__(16) u16 Vs[64 * 72];     // V^T tile [d][kk], stride 72 (padded)
  __shared__ __align__(16) int Mshi[2048];
  const int tid = threadIdx.x, w = tid >> 6, lane = tid & 63;
  const int quad = lane >> 4, l15 = lane & 15;
  const int b = blockIdx.z, h = blockIdx.y, q0 = blockIdx.x * 256;
  const int srow = lane >> 3, scol = (lane & 7) * 8;

  // stage Q tile (256x64, stride 64) + mask ints
#pragma unroll
  for (int r = 0; r < 8; ++r) {
    int c = w * 8 + r;
    async_cp16(Qb + (size_t)(b * 2048 + q0 + c * 8 + srow) * 1024 + h * 64 + scol,
               (char*)QPs + c * 1024);
  }
#pragma unroll
  for (int r = 0; r < 2; ++r) {
    int c = w * 2 + r;
    async_cp16(mask + b * 2048 + c * 256 + lane * 4, (char*)Mshi + c * 1024);
  }
  __syncthreads();

  // Q fragments in registers (wave's own 64 rows); also valid as B-operand of S^T
  bf16x8 aq[4][2];
#pragma unroll
  for (int i = 0; i < 4; ++i)
#pragma unroll
    for (int ks = 0; ks < 2; ++ks)
      aq[i][ks] = *(const bf16x8*)(const void*)(QPs + (w * 64 + i * 16 + l15) * 64 + ks * 32 + quad * 8);

  const f32x4 fz = {0.f, 0.f, 0.f, 0.f};
  f32x4 o[4][4];                 // O^T accum: [d-tile][q-tile], row d=quad*4+e, col q=l15
  float rs[4] = {0.f, 0.f, 0.f, 0.f};   // per-lane partial row sums (quad-partitioned over kk)
#pragma unroll
  for (int dt = 0; dt < 4; ++dt)
#pragma unroll
    for (int i = 0; i < 4; ++i) o[dt][i] = fz;

  for (int kt = 0; kt < 2048; kt += 64) {
    __syncthreads();
    int4 vg[2];
#pragma unroll
    for (int r = 0; r < 2; ++r) {
      int c = w * 2 + r;
      async_cp16(Kb + (size_t)(b * 2048 + kt + c * 8 + srow) * 1024 + h * 64 + scol,
                 (char*)Ks + c * 1024);
      vg[r] = *(const int4*)(const void*)(
          Vt + ((size_t)(b * 16 + h) * 64 + c * 8 + srow) * 2048 + kt + scol);
    }
#pragma unroll
    for (int r = 0; r < 2; ++r) {
      int c = w * 2 + r;
      *(int4*)(void*)((char*)Vs + (c * 8 + srow) * 144 + (lane & 7) * 16) = vg[r];
    }
    __syncthreads();

    bf16x8 kb[4][2];             // K A-frags: m=kk=l15, k=d
#pragma unroll
    for (int kkt = 0; kkt < 4; ++kkt)
#pragma unroll
      for (int ks = 0; ks < 2; ++ks)
        kb[kkt][ks] = *(const bf16x8*)(const void*)(Ks + (kkt * 16 + l15) * 64 + ks * 32 + quad * 8);

#pragma unroll
    for (int kkt = 0; kkt < 4; ++kkt) {
      // mask multipliers for this lane's 4 kk rows (broadcast read)
      int4 mi = *(const int4*)(Mshi + kt + kkt * 16 + quad * 4);
      float m0 = (float)(mi.x ^ 1), m1 = (float)(mi.y ^ 1);
      float m2 = (float)(mi.z ^ 1), m3 = (float)(mi.w ^ 1);

      s16x4 pf[4];
#pragma unroll
      for (int i = 0; i < 4; ++i) {
        f32x4 st = MFMA32(kb[kkt][0], aq[i][0], fz);
        st = MFMA32(kb[kkt][1], aq[i][1], st);
        float p0 = exp2f(st[0]) * m0, p1 = exp2f(st[1]) * m1;
        float p2 = exp2f(st[2]) * m2, p3 = exp2f(st[3]) * m3;
        rs[i] += (p0 + p1) + (p2 + p3);
        union { unsigned u[2]; s16x4 s; } pk;
        pk.u[0] = pack2bf(p0, p1);
        pk.u[1] = pack2bf(p2, p3);
        pf[i] = pk.s;
      }
#pragma unroll
      for (int dt = 0; dt < 4; ++dt) {
        s16x4 va = *(const s16x4*)(const void*)(Vs + (dt * 16 + l15) * 72 + kkt * 16 + quad * 4);
#pragma unroll
        for (int i = 0; i < 4; ++i)
          o[dt][i] = MFMA16(va, pf[i], o[dt][i]);
      }
    }
  }

  // row sums: reduce the 4 quad-partitions
  float inv[4];
#pragma unroll
  for (int i = 0; i < 4; ++i) {
    float v = rs[i];
    v += __shfl_xor(v, 16, 64);
    v += __shfl_xor(v, 32, 64);
    inv[i] = 1.0f / v;
  }

  // epilogue: un-transpose O^T via wave-private LDS strip (stride 72 u16 = 144B, 16B-aligned)
  u16* strip = QPs + w * 64 * 72;
#pragma unroll
  for (int dt = 0; dt < 4; ++dt)
#pragma unroll
    for (int i = 0; i < 4; ++i) {
      union { unsigned u[2]; s16x4 s; } pk;
      pk.u[0] = pack2bf(o[dt][i][0] * inv[i], o[dt][i][1] * inv[i]);
      pk.u[1] = pack2bf(o[dt][i][2] * inv[i], o[dt][i][3] * inv[i]);
      *(s16x4*)(void*)(strip + (i * 16 + l15) * 72 + dt * 16 + quad * 4) = pk.s;
    }
  // coalesced store: 8 lanes x 16B per q-row
#pragma unroll
  for (int pass = 0; pass < 8; ++pass) {
    int row = pass * 8 + (lane >> 3), oct = lane & 7;
    int4 v = *(const int4*)(const void*)(strip + row * 72 + oct * 8);
    *(int4*)(Ob + (size_t)(b * 2048 + q0 + w * 64 + row) * 1024 + h * 64 + oct * 8) = v;
  }
}

// ---------- launch ----------
extern "C" void kernel_launch(void* const* d_in, const int* in_sizes, int n_in,
                              void* d_out, int out_size, void* d_ws, size_t ws_size,
                              hipStream_t stream) {
  const float* x    = (const float*)d_in[0];
  const float* ctx  = (const float*)d_in[1];
  const int*   mask = (const int*)d_in[2];
  const float* lnqw = (const float*)d_in[3];
  const float* lnqb = (const float*)d_in[4];
  const float* lncw = (const float*)d_in[5];
  const float* lncb = (const float*)d_in[6];
  const float* Wq   = (const float*)d_in[7];
  const float* Wk   = (const float*)d_in[8];
  const float* Wv   = (const float*)d_in[9];
  const float* Wo   = (const float*)d_in[10];
  const float* tau  = (const float*)d_in[11];
  float* out = (float*)d_out;
  char* ws = (char*)d_ws;
  const size_t MB = 1024 * 1024;

  u16* qin  = (u16*)(ws + 0 * MB);    // 16 MB; reused as attn-out later
  u16* kvin = (u16*)(ws + 16 * MB);   // 16 MB
  u16* WqT  = (u16*)(ws + 32 * MB);   // 2 MB each
  u16* WkT  = (u16*)(ws + 34 * MB);
  u16* WvT  = (u16*)(ws + 36 * MB);
  u16* WoT  = (u16*)(ws + 38 * MB);
  u16* qbf  = (u16*)(ws + 40 * MB);   // 16 MB
  u16* kbf  = (u16*)(ws + 56 * MB);   // 16 MB
  u16* vT   = (u16*)(ws + 72 * MB);   // 16 MB  (total 88 MB — proven footprint)
  float* scr = out;                   // d_out (32 MB f32) as V-projection scratch
  u16* attn = qin;                    // qin dead after first GEMM

  ln_cast<<<8192, 256, 0, stream>>>(x,   lnqw, lnqb, qin);
  ln_cast<<<8192, 256, 0, stream>>>(ctx, lncw, lncb, kvin);
  wtrans<<<dim3(16, 16), 256, 0, stream>>>(Wq, WqT);
  wtrans<<<dim3(16, 16), 256, 0, stream>>>(Wk, WkT);
  wtrans<<<dim3(16, 16), 256, 0, stream>>>(Wv, WvT);
  wtrans<<<dim3(16, 16), 256, 0, stream>>>(Wo, WoT);

  gemm_l2n<<<dim3(8, 64), 256, 0, stream>>>(qin,  WqT, qbf, tau, 1);
  gemm_l2n<<<dim3(8, 64), 256, 0, stream>>>(kvin, WkT, kbf, tau, 0);

  gemm_bt<<<dim3(8, 64), 256, 0, stream>>>(kvin, WvT, scr, 8192, 1024, 1024);
  vtrans<<<dim3(32, 16, 4), 256, 0, stream>>>(scr, vT);

  flash_attn4<<<dim3(8, 16, 4), 256, 0, stream>>>(qbf, kbf, vT, mask, attn);

  gemm_bt<<<dim3(8, 64), 256, 0, stream>>>(attn, WoT, out, 8192, 1024, 1024);
}